// Round 2
// 363.677 us; speedup vs baseline: 1.0222x; 1.0222x over previous
//
#include <hip/hip_runtime.h>

// Problem constants (from reference)
#define Bc 4
#define Nc 16384
#define Hc 8
#define Dc 128
#define Kc 32
#define STRIDEc 16
#define Mc 1023          // (N-K)/STRIDE + 1
#define HD4 (Hc * Dc / 4)   // float4 elements per n-row = 256
#define WPB 2               // windows per block
#define BLKS_PER_B 512      // ceil(Mc / WPB)
#define GRIDc (Bc * BLKS_PER_B)  // 2048 blocks (% 8 == 0 -> bijective XCD swizzle)

// Decomposition: out[m] = S0(chunk m) + S1(chunk m+1) + bias, all * 1/K
//   S0(j) = sum_{i<16} x[16j+i] * w[i]
//   S1(j) = sum_{i<16} x[16j+i] * w[16+i]
// Each block computes 2 consecutive windows from 3 chunks (48 rows) ->
// x read amplification 1.5x instead of 2x, no LDS, no __syncthreads.
__global__ __launch_bounds__(256, 4) void compress_kv_kernel(
    const float* __restrict__ x,
    const float* __restrict__ w,
    const float* __restrict__ pe,
    float* __restrict__ out)
{
    // XCD-aware swizzle: blocks with the same (bid % 8) land on the same XCD;
    // give each XCD a contiguous stripe of the m-range so the shared boundary
    // chunks between neighboring blocks hit the same per-XCD L2.
    const int bid = blockIdx.x;
    const int swz = (bid & 7) * (GRIDc / 8) + (bid >> 3);

    const int b  = swz >> 9;                    // / BLKS_PER_B
    const int m0 = (swz & (BLKS_PER_B - 1)) * WPB;
    const bool two = (m0 + 1 < Mc);             // last block per b does 1 window

    const int tid = threadIdx.x;
    const int d4  = tid & 31;                   // float4 lane over D (D/4 = 32)
    const int h   = tid >> 5;                   // 0..7

    // Weights: uniform address + restrict -> scalar loads (SGPR-resident).
    float wr[Kc];
    #pragma unroll
    for (int k = 0; k < Kc; ++k) wr[k] = w[k];

    // Per-thread bias for this d4: sum_k pe[k, 4*d4 .. 4*d4+3] * w[k].
    // pe is 16 KB -> L1-resident after first touch; no LDS, no sync.
    const float4* __restrict__ pe4 = (const float4*)pe;
    float4 bias = make_float4(0.f, 0.f, 0.f, 0.f);
    #pragma unroll
    for (int k = 0; k < Kc; ++k) {
        float4 p = pe4[k * (Dc / 4) + d4];
        float a = wr[k];
        bias.x += p.x * a; bias.y += p.y * a;
        bias.z += p.z * a; bias.w += p.w * a;
    }

    const float4* __restrict__ x4 = (const float4*)x;
    // base in float4 units: ((b*N + m0*16)*H + h) * (D/4) + d4
    int base = ((b * Nc + m0 * STRIDEc) * Hc + h) * (Dc / 4) + d4;

    float4 s0p, s0, s1;

    // chunk 0: S0 only
    s0 = make_float4(0.f, 0.f, 0.f, 0.f);
    #pragma unroll
    for (int i = 0; i < 16; ++i) {
        float4 xv = x4[base + i * HD4];
        float a = wr[i];
        s0.x += xv.x * a; s0.y += xv.y * a;
        s0.z += xv.z * a; s0.w += xv.w * a;
    }
    s0p = s0;
    base += 16 * HD4;

    // chunk 1: S0 and S1; emit window m0
    s0 = make_float4(0.f, 0.f, 0.f, 0.f);
    s1 = make_float4(0.f, 0.f, 0.f, 0.f);
    #pragma unroll
    for (int i = 0; i < 16; ++i) {
        float4 xv = x4[base + i * HD4];
        float a = wr[i], c = wr[16 + i];
        s0.x += xv.x * a; s0.y += xv.y * a;
        s0.z += xv.z * a; s0.w += xv.w * a;
        s1.x += xv.x * c; s1.y += xv.y * c;
        s1.z += xv.z * c; s1.w += xv.w * c;
    }

    float4* __restrict__ out4 = (float4*)out;
    int obase = ((b * Mc + m0) * Hc + h) * (Dc / 4) + d4;
    const float inv = 1.0f / (float)Kc;

    float4 r;
    r.x = (s0p.x + s1.x + bias.x) * inv;
    r.y = (s0p.y + s1.y + bias.y) * inv;
    r.z = (s0p.z + s1.z + bias.z) * inv;
    r.w = (s0p.w + s1.w + bias.w) * inv;
    out4[obase] = r;

    if (two) {
        // chunk 2: S1 only; emit window m0+1
        s0p = s0;
        base += 16 * HD4;
        s1 = make_float4(0.f, 0.f, 0.f, 0.f);
        #pragma unroll
        for (int i = 0; i < 16; ++i) {
            float4 xv = x4[base + i * HD4];
            float c = wr[16 + i];
            s1.x += xv.x * c; s1.y += xv.y * c;
            s1.z += xv.z * c; s1.w += xv.w * c;
        }
        r.x = (s0p.x + s1.x + bias.x) * inv;
        r.y = (s0p.y + s1.y + bias.y) * inv;
        r.z = (s0p.z + s1.z + bias.z) * inv;
        r.w = (s0p.w + s1.w + bias.w) * inv;
        out4[obase + HD4] = r;
    }
}

extern "C" void kernel_launch(void* const* d_in, const int* in_sizes, int n_in,
                              void* d_out, int out_size, void* d_ws, size_t ws_size,
                              hipStream_t stream) {
    const float* x  = (const float*)d_in[0];
    const float* w  = (const float*)d_in[1];
    const float* pe = (const float*)d_in[2];
    float* out = (float*)d_out;

    compress_kv_kernel<<<GRIDc, 256, 0, stream>>>(x, w, pe, out);
}